// Round 17
// baseline (397.852 us; speedup 1.0000x reference)
//
#include <hip/hip_runtime.h>

#define NCAM 6
#define FC   128
#define FH_  32
#define FW_  88
#define NPIX (FH_*FW_)        // 2816
#define PH   34
#define PW   92               // padded width
#define PPIX (PH*PW)          // 3128
#define ND   41
#define X3D  42               // 41 depth + 1 opacity planes
#define OUTC 128
#define GTOT (NCAM*NPIX)      // 16896
#define BEVH 100
#define BEVW 100
#define NPXB (BEVH*BEVW)      // 10000
#define NTILE 25              // 25x25 tiles of 4x4 px
#define NWORD 264             // 16896/64 mask words per tile
#define NMASKW (NTILE*NTILE*NWORD)  // 165000 u64
#define WCAP  70000           // worklist capacity (chunks)
#define CSIZE 64              // hits per chunk
#define CBLK  2048            // composite blocks (contiguous chunk ranges)

// ---- ws layout (float offsets). ----
#define SZA     (NCAM*FC*PPIX)           // 2402304
#define WS_A    256
#define C1OFF   1201152                   // float offset of conv1out16
#define WS_RB   (WS_A  + SZA)            // colors16 (bf16) lives here
#define WS_X3   (WS_RB + SZA)            // wcvt (early) -> x3d fp32 -> aux ints
#define WS_GS   (WS_X3 + NCAM*X3D*NPIX)  // gauss params 16896*8
#define WS_WL   (WS_GS + GTOT*8)         // worklist ints
#define WS_BASE (WS_WL + WCAP)           // MASKS (early) then per-chunk bases (late)
#define WELEM   (9*128*128)              // 147456 elems per wcvt array

typedef __attribute__((ext_vector_type(8))) short bf16x8;
typedef __attribute__((ext_vector_type(4))) float f32x4;

__device__ inline unsigned short f2bf(float f) {
    unsigned u = __float_as_uint(f);
    u += 0x7fffu + ((u >> 16) & 1u);     // round-to-nearest-even
    return (unsigned short)(u >> 16);
}
__device__ inline float bf2f(unsigned short h) {
    unsigned u = ((unsigned)h) << 16;
    return __uint_as_float(u);
}

__device__ inline void inv3x3(const float* m, float* o) {
    float a=m[0],b=m[1],c=m[2],d=m[3],e=m[4],f=m[5],g=m[6],h=m[7],i=m[8];
    float A=e*i-f*h, B=c*h-b*i, C=b*f-c*e;
    float Dd=f*g-d*i, E=a*i-c*g, F=c*d-a*f;
    float Gg=d*h-e*g, H=b*g-a*h, I=a*e-b*d;
    float r = 1.0f/(a*A + b*Dd + c*Gg);
    o[0]=A*r; o[1]=B*r; o[2]=C*r; o[3]=Dd*r; o[4]=E*r; o[5]=F*r;
    o[6]=Gg*r; o[7]=H*r; o[8]=I*r;
}

// convert conv weights fp32 [co][ci][3][3] -> bf16 [tap][co][ci] (both layers)
__global__ __launch_bounds__(256) void prep_weights_kernel(const float* __restrict__ w1,
        const float* __restrict__ w2, unsigned short* __restrict__ wc1,
        unsigned short* __restrict__ wc2) {
    int idx = blockIdx.x*256 + threadIdx.x;
    if (idx >= 2*WELEM) return;
    const float* src = (idx < WELEM) ? w1 : w2;
    unsigned short* dst = (idx < WELEM) ? wc1 : wc2;
    int e = (idx < WELEM) ? idx : idx - WELEM;
    int tap = e / (128*128), r = e - tap*(128*128);
    int co = r >> 7, ci = r & 127;
    int dy = tap / 3, dx = tap - dy*3;
    dst[e] = f2bf(src[((co*128 + ci)*3 + dy)*3 + dx]);
}

// transpose-pad: img fp32 [n][ci][y][x] -> pad16 bf16 [n][y][xp][ci] with zero
// borders; also zeros conv1out16 borders, out+ngp, MASKS (memset fold).
__global__ __launch_bounds__(256) void pad_tr_kernel(const float* __restrict__ src,
        unsigned short* __restrict__ pad16, unsigned short* __restrict__ c1o16,
        float* __restrict__ outp, unsigned long long* __restrict__ masks) {
    __shared__ unsigned short lds[92*132];
    const int bid = blockIdx.x;               // 0..203 = (n, y)
    const int n = bid / PH, y = bid - n*PH;
    const int t = threadIdx.x;
    // memset fold: out planes + ngp, masks
    for (int j = bid*256 + t; j <= NPXB*OUTC; j += 204*256) outp[j] = 0.0f;
    for (int j = bid*256 + t; j < NMASKW; j += 204*256) masks[j] = 0ull;

    unsigned short* prow = pad16 + ((size_t)n*PPIX + y*PW)*128;
    unsigned short* crow = c1o16 + ((size_t)n*PPIX + y*PW)*128;
    if (y == 0 || y == PH-1) {
        for (int j = t; j < PW*128; j += 256) { prow[j] = 0; crow[j] = 0; }
        return;
    }
    // zero border cols xp in {0,89,90,91} of lds, and of conv1out16 row
    for (int j = t; j < 4*128; j += 256) {
        int bc = j >> 7, ci = j & 127;
        int xp = (bc == 0) ? 0 : (88 + bc);
        lds[xp*132 + ci] = 0;
        crow[xp*128 + ci] = 0;
    }
    // read src row (y-1 in true coords), coalesced per ci-row; write lds[xp][ci]
    const float* sp = src + (size_t)n*FC*NPIX + (size_t)(y-1)*FW_;
    for (int j = t; j < 128*FW_; j += 256) {
        int ci = j / FW_, x = j - ci*FW_;
        lds[(x+1)*132 + ci] = f2bf(sp[(size_t)ci*NPIX + x]);
    }
    __syncthreads();
    // write pad16 row contiguously (ushort scalar stores, coalesced)
    for (int j = t; j < PW*128; j += 256) {
        int xp = j >> 7, ci = j & 127;
        prow[j] = lds[xp*132 + ci];
    }
}

// 3x3 conv as MFMA GEMM. v3: M-split (by: y-row x m-half) AND co z-split to 4
// quarters with 128-thread blocks (2 waves). Grid (6,64,4) = 1536 blocks
// (6/CU). Same 3072 waves / 108 MFMA per wave as v2; per-output K-order
// identical -> bit-identical results. Finer packaging for CU makespan.
__global__ __launch_bounds__(128) void conv3x3_mfma_kernel(
        const unsigned short* __restrict__ in16, unsigned short* __restrict__ out16,
        const unsigned short* __restrict__ wcvt,
        const float* __restrict__ cb, const float* __restrict__ bg,
        const float* __restrict__ bb, const float* __restrict__ bm,
        const float* __restrict__ bv) {
    const int n = blockIdx.x;
    const int y = (blockIdx.y >> 1) + 1;     // output padded row 1..32
    const int mh = blockIdx.y & 1;           // m-half: column tiles mh*3..mh*3+2
    const int quarter = blockIdx.z;          // co quarter (32 co each)
    const int t = threadIdx.x;
    const int lane = t & 63, wv = t >> 6;    // wv 0..1
    const int n16 = lane & 15, kb = lane >> 4;
    const int co = quarter*32 + wv*16 + n16; // this lane's output channel
    const float scale = bg[co] * rsqrtf(bv[co] + 1e-3f);
    const float shift = (cb[co] - bm[co]) * scale + bb[co];

    const unsigned short* ibase = in16 + (size_t)n*PPIX*128;
    f32x4 acc[3];
    #pragma unroll
    for (int m = 0; m < 3; ++m) acc[m] = (f32x4){0.f,0.f,0.f,0.f};

    for (int kc = 0; kc < 4; ++kc) {
        #pragma unroll
        for (int tap = 0; tap < 9; ++tap) {
            const int dy = tap / 3, dx = tap - dy*3;
            bf16x8 bfrag = *(const bf16x8*)(wcvt + ((size_t)(tap*128 + co))*128 + kc*32 + kb*8);
            const unsigned short* arow = ibase + (size_t)(y + dy - 1)*PW*128 + kc*32 + kb*8;
            #pragma unroll
            for (int m = 0; m < 3; ++m) {
                int col = (mh*3 + m)*16 + n16 + dx;  // input padded col
                col = min(col, 91);
                bf16x8 afrag = *(const bf16x8*)(arow + (size_t)col*128);
                acc[m] = __builtin_amdgcn_mfma_f32_16x16x32_bf16(afrag, bfrag, acc[m], 0, 0, 0);
            }
        }
    }
    // epilogue: C row(px) = kb*4 + r, col = n16 -> store out16[y][xp][co]
    unsigned short* obase = out16 + ((size_t)n*PPIX + y*PW)*128 + co;
    #pragma unroll
    for (int m = 0; m < 3; ++m) {
        #pragma unroll
        for (int r = 0; r < 4; ++r) {
            int xp = 1 + (mh*3 + m)*16 + kb*4 + r;
            if (xp <= 88) {
                float v = fmaxf(fmaf(acc[m][r], scale, shift), 0.0f);
                obase[(size_t)xp*128] = f2bf(v);
            }
        }
    }
}

// 1x1 conv from bf16 TRANSPOSED input [n][pp][ci] (ci-contiguous per px).
__global__ __launch_bounds__(256) void conv1x1_kernel(const unsigned short* __restrict__ in16,
        float* __restrict__ x3d, unsigned short* __restrict__ colors16,
        const float* __restrict__ w, const float* __restrict__ b) {
    const int n   = blockIdx.x;
    const int px  = blockIdx.y * 256 + threadIdx.x;
    const int y   = px / FW_, x = px - y*FW_;
    const int pp  = (y+1)*PW + (x+1);
    const unsigned short* ip = in16 + ((size_t)n*PPIX + pp)*128;
    if (blockIdx.z < 6) {
        const int co0 = blockIdx.z * 7;
        const float* wr[7];
        float acc[7];
        #pragma unroll
        for (int k=0;k<7;k++) {
            int co = co0 + k;
            wr[k]  = w + (size_t)co*FC;
            acc[k] = b[co];
        }
        for (int c8 = 0; c8 < 16; ++c8) {
            uint4 pk = *(const uint4*)(ip + c8*8);
            const unsigned* pw = (const unsigned*)&pk;
            #pragma unroll
            for (int j = 0; j < 4; ++j) {
                float v0 = bf2f((unsigned short)(pw[j] & 0xffffu));
                float v1 = bf2f((unsigned short)(pw[j] >> 16));
                int ci = c8*8 + j*2;
                #pragma unroll
                for (int k=0;k<7;k++) {
                    acc[k] = fmaf(wr[k][ci],   v0, acc[k]);
                    acc[k] = fmaf(wr[k][ci+1], v1, acc[k]);
                }
            }
        }
        #pragma unroll
        for (int k=0;k<7;k++)
            x3d[((size_t)n*X3D + co0 + k)*NPIX + px] = acc[k];
    } else {
        const int c0  = (blockIdx.z - 6) * 8;
        const int co0 = X3D + c0;
        const float* wr[8];
        float acc[8];
        #pragma unroll
        for (int k=0;k<8;k++) {
            int co = co0 + k;
            wr[k]  = w + (size_t)co*FC;
            acc[k] = b[co];
        }
        for (int c8 = 0; c8 < 16; ++c8) {
            uint4 pk = *(const uint4*)(ip + c8*8);
            const unsigned* pw = (const unsigned*)&pk;
            #pragma unroll
            for (int j = 0; j < 4; ++j) {
                float v0 = bf2f((unsigned short)(pw[j] & 0xffffu));
                float v1 = bf2f((unsigned short)(pw[j] >> 16));
                int ci = c8*8 + j*2;
                #pragma unroll
                for (int k=0;k<8;k++) {
                    acc[k] = fmaf(wr[k][ci],   v0, acc[k]);
                    acc[k] = fmaf(wr[k][ci+1], v1, acc[k]);
                }
            }
        }
        unsigned short h[8];
        #pragma unroll
        for (int k=0;k<8;k++) h[k] = f2bf(acc[k]);
        uint4 pk;
        pk.x = (unsigned)h[0] | ((unsigned)h[1] << 16);
        pk.y = (unsigned)h[2] | ((unsigned)h[3] << 16);
        pk.z = (unsigned)h[4] | ((unsigned)h[5] << 16);
        pk.w = (unsigned)h[6] | ((unsigned)h[7] << 16);
        *(uint4*)(colors16 + (((size_t)(n*NPIX + px)) << 7) + c0) = pk;
    }
}

// cam consts (per-block LDS) + softmax moments + splat params. 66 blocks.
__global__ __launch_bounds__(256) void moments_kernel(const float* __restrict__ x3,
        const float* __restrict__ rot, const float* __restrict__ tr,
        const float* __restrict__ intr, const float* __restrict__ prot,
        const float* __restrict__ ptr_, float* __restrict__ gauss,
        float* __restrict__ ng) {
    __shared__ float cc[24];
    const int n = blockIdx.x / 11;
    if (threadIdx.x == 0) {
        float M1[9], Ki[9];
        inv3x3(prot + n*9, M1);
        inv3x3(intr + n*9, Ki);
        const float* R = rot + n*9;
        #pragma unroll
        for (int i=0;i<9;i++) cc[i] = M1[i];
        #pragma unroll
        for (int i=0;i<3;i++) cc[9+i] = ptr_[n*3+i];
        #pragma unroll
        for (int i=0;i<3;i++)
            #pragma unroll
            for (int j=0;j<3;j++)
                cc[12+i*3+j] = R[i*3+0]*Ki[0+j] + R[i*3+1]*Ki[3+j] + R[i*3+2]*Ki[6+j];
        #pragma unroll
        for (int i=0;i<3;i++) cc[21+i] = tr[n*3+i];
    }
    __syncthreads();
    const int gi = blockIdx.x*256 + threadIdx.x;
    const int p  = gi - n*NPIX;
    const int h  = p / FW_, xp = p - h*FW_;
    float u = xp * (703.0f/87.0f);
    float v = h  * (255.0f/31.0f);
    float fx = u - cc[9], fy = v - cc[10], fz = -cc[11];
    float p0x = cc[0]*fx + cc[1]*fy + cc[2]*fz;
    float p0y = cc[3]*fx + cc[4]*fy + cc[5]*fz;
    float p0z = cc[6]*fx + cc[7]*fy + cc[8]*fz;
    const float* lg = x3 + (size_t)n*X3D*NPIX + p;

    float lgv[ND];
    #pragma unroll
    for (int d=0; d<ND; ++d) lgv[d] = lg[(size_t)d*NPIX];

    float mxl = -1e30f;
    #pragma unroll
    for (int d=0; d<ND; ++d) mxl = fmaxf(mxl, lgv[d]);

    float s=0.f, sgx=0.f, sgy=0.f;
    #pragma unroll
    for (int d=0; d<ND; ++d) {
        float e  = __expf(lgv[d] - mxl);
        lgv[d] = e;
        float dz = 4.0f + (float)d;
        float pz = p0z + dz*cc[8];
        float px = (p0x + dz*cc[2]) * pz;
        float py = (p0y + dz*cc[5]) * pz;
        float gx = cc[12]*px + cc[13]*py + cc[14]*pz + cc[21];
        float gy = cc[15]*px + cc[16]*py + cc[17]*pz + cc[22];
        s += e; sgx += e*gx; sgy += e*gy;
    }
    float inv_s = 1.0f/s;
    float mex = sgx*inv_s, mey = sgy*inv_s;
    float cxx=0.f, cxy=0.f, cyy=0.f;
    #pragma unroll
    for (int d=0; d<ND; ++d) {
        float e  = lgv[d];
        float dz = 4.0f + (float)d;
        float pz = p0z + dz*cc[8];
        float px = (p0x + dz*cc[2]) * pz;
        float py = (p0y + dz*cc[5]) * pz;
        float gx = cc[12]*px + cc[13]*py + cc[14]*pz + cc[21];
        float gy = cc[15]*px + cc[16]*py + cc[17]*pz + cc[22];
        float dxv = gx - mex, dyv = gy - mey;
        cxx += e*dxv*dxv; cxy += e*dxv*dyv; cyy += e*dyv*dyv;
    }
    const float k9 = inv_s * (1.0f/9.0f);
    cxx *= k9; cxy *= k9; cyy *= k9;

    float lo = lg[(size_t)ND*NPIX];
    float op = 1.0f/(1.0f + __expf(-lo));
    bool mask = op > 0.05f;

    const float SC = 0.02f, SH = 50.0f, SW = 50.0f;
    float my = -SH*(mey*SC) + 50.0f;
    float mx = -SW*(mex*SC) + 50.0f;
    float a  = SH*SH*(cyy*SC*SC) + 0.3f;
    float b  = SH*SW*(cxy*SC*SC);
    float c  = SW*SW*(cxx*SC*SC) + 0.3f;
    float det = a*c - b*b;
    bool valid = mask && (det > 0.0f);
    float A, B2, C, qm, ri, rj;
    if (valid) {
        float idet = 1.0f/det;
        A = c*idet; B2 = -2.0f*b*idet; C = a*idet;
        qm = 2.0f*__logf(255.0f*op);
        ri = sqrtf(qm*a); rj = sqrtf(qm*c);
    } else { A=B2=C=0.f; qm=-1.0f; ri=-1e30f; rj=-1e30f; }
    float* gp = gauss + (size_t)gi*8;
    gp[0]=my; gp[1]=mx; gp[2]=A; gp[3]=B2; gp[4]=C; gp[5]=qm; gp[6]=ri; gp[7]=rj;

    unsigned long long bal = __ballot(mask);
    if ((threadIdx.x & 63) == 0) atomicAdd(ng, (float)__popcll(bal));
}

// tile bitmask scatter, 4x parallel: thread = (gaussian, ti-quarter).
__global__ __launch_bounds__(256) void scatter_masks_kernel(const float* __restrict__ gauss,
        unsigned long long* __restrict__ masks) {
    const int idx = blockIdx.x*256 + threadIdx.x;    // 0..67583
    const int g = idx >> 2, q = idx & 3;
    const float4 g0 = *(const float4*)(gauss + ((size_t)g << 3));      // my,mx,A,2B
    const float4 g1 = *(const float4*)(gauss + ((size_t)g << 3) + 4);  // C,qm,ri,rj
    if (g1.y < 0.0f) return;
    const float my = g0.x, mx = g0.y, A = g0.z, B = 0.5f*g0.w, C = g1.x, qm = g1.y, ri = g1.z;
    const float invC = 1.0f / C;
    const float k2 = C*A - B*B;          // > 0
    int ti0 = max(0, (int)floorf((my - ri) * 0.25f));
    int ti1 = min(NTILE-1, (int)floorf((my + ri) * 0.25f));
    int len = ti1 - ti0 + 1;
    int ta = ti0 + (len*q) / 4;
    int tb = ti0 + (len*(q+1)) / 4;      // disjoint union over q=0..3
    const int wi = g >> 6;
    const unsigned long long bit = 1ull << (g & 63);
    for (int ti = ta; ti < tb; ++ti) {
        float jmn = 1e30f, jmx = -1e30f;
        #pragma unroll
        for (int r = 0; r < 4; ++r) {
            int i = 4*ti + r;
            if (i < 0 || i > 99) continue;
            float di = (float)i - my;
            float disc = C*qm - k2*di*di;
            if (disc < 0.0f) continue;
            float sd = sqrtf(disc);
            float jc = -B*di;
            jmn = fminf(jmn, (jc - sd)*invC + mx);
            jmx = fmaxf(jmx, (jc + sd)*invC + mx);
        }
        if (jmx < jmn) continue;
        int jl = max(0, (int)ceilf(jmn));
        int jh = min(99, (int)floorf(jmx));
        if (jl > jh) continue;
        for (int tj = (jl >> 2); tj <= (jh >> 2); ++tj)
            atomicOr(&masks[(size_t)(ti*NTILE + tj)*NWORD + wi], bit);
    }
}

// per-tile hit count
__global__ __launch_bounds__(256) void cnt_kernel(const unsigned long long* __restrict__ masks,
                                                  int* __restrict__ cnt) {
    __shared__ int sc;
    const int tile = blockIdx.x, t = threadIdx.x;
    if (t == 0) sc = 0;
    __syncthreads();
    if (t < NWORD) atomicAdd(&sc, __popcll(masks[(size_t)tile*NWORD + t]));
    __syncthreads();
    if (t == 0) cnt[tile] = sc;
}

// parallel exclusive scans over 625 tiles (single 640-thread block, shfl scan)
__global__ __launch_bounds__(640) void scan_kernel(const int* __restrict__ cnt,
        int* __restrict__ off, int* __restrict__ choff, int* __restrict__ nwork) {
    __shared__ int wsum[16], wsum2[16];
    const int t = threadIdx.x;
    const int lane = t & 63, wv = t >> 6;
    int c  = (t < NTILE*NTILE) ? cnt[t] : 0;
    int ch = (c + CSIZE-1) >> 6;
    int v = c, v2 = ch;
    #pragma unroll
    for (int o = 1; o < 64; o <<= 1) {
        int u  = __shfl_up(v,  (unsigned)o, 64);
        int u2 = __shfl_up(v2, (unsigned)o, 64);
        if (lane >= o) { v += u; v2 += u2; }
    }
    if (lane == 63) { wsum[wv] = v; wsum2[wv] = v2; }
    __syncthreads();
    int pre = 0, pre2 = 0;
    for (int w2 = 0; w2 < wv; ++w2) { pre += wsum[w2]; pre2 += wsum2[w2]; }
    int inc = v + pre, inc2 = v2 + pre2;
    if (t < NTILE*NTILE) { off[t] = inc - c; choff[t] = inc2 - ch; }
    if (t == NTILE*NTILE - 1) {
        off[NTILE*NTILE] = inc;
        choff[NTILE*NTILE] = inc2;
        nwork[0] = (inc2 > WCAP) ? WCAP : inc2;
    }
}

// expand bitmasks -> dense ordered hit lists + chunk worklist
__global__ __launch_bounds__(256) void fill_kernel(const unsigned long long* __restrict__ masks,
        const int* __restrict__ cnt, const int* __restrict__ off, const int* __restrict__ choff,
        unsigned short* __restrict__ list, int* __restrict__ wl) {
    __shared__ unsigned long long sw[NWORD];
    __shared__ int wpre[NWORD];
    const int tile = blockIdx.x, t = threadIdx.x;
    if (t < NWORD) sw[t] = masks[(size_t)tile*NWORD + t];
    __syncthreads();
    if (t == 0) {
        int run = 0;
        for (int w2 = 0; w2 < NWORD; ++w2) { wpre[w2] = run; run += __popcll(sw[w2]); }
    }
    __syncthreads();
    if (t < NWORD) {
        unsigned long long m = sw[t];
        int pos = off[tile] + wpre[t], base = t << 6;
        while (m) { int b = __builtin_ctzll(m); m &= m - 1; list[pos++] = (unsigned short)(base + b); }
    }
    int nch = (cnt[tile] + CSIZE-1)/CSIZE;
    int c0 = choff[tile];
    if (t < nch && c0 + t < WCAP) wl[c0 + t] = (tile << 9) | t;
}

__device__ inline float eval_alpha(const float4 g0, const float4 g1, float fi, float fj) {
    float dI = fi - g0.x, dJ = fj - g0.y;
    float q = dI*(g0.z*dI + g0.w*dJ) + g1.x*dJ*dJ;     // g0.w = 2B
    if (q < 0.0f || q > g1.y) return 0.0f;
    return fminf(0.99f, 0.003921568627f * __expf(0.5f*(g1.y - q)));
}

// per chunk: per-px PRODUCT of (1-alpha) -> BASE[e][px] (pre-prefix).
__global__ __launch_bounds__(256) void chunk_sums_kernel(const float* __restrict__ gauss,
        const unsigned short* __restrict__ list, const int* __restrict__ cnt,
        const int* __restrict__ off, const int* __restrict__ wl, const int* __restrict__ nwork,
        float* __restrict__ base) {
    const int nw = nwork[0];
    const int lane = threadIdx.x & 63;
    const int wid  = (blockIdx.x * 256 + threadIdx.x) >> 6;   // global wave id
    const int nwv  = (gridDim.x * 256) >> 6;
    const int px = lane & 15, kg = lane >> 4;
    for (int e = wid; e < nw; e += nwv) {
        int v = wl[e], tile = v >> 9, c = v & 511;
        int hbase = off[tile] + (c << 6);
        int nh = min(CSIZE, cnt[tile] - (c << 6));
        const int i0 = (tile / NTILE) * 4, j0 = (tile % NTILE) * 4;
        const float fi = (float)(i0 + (px >> 2)), fj = (float)(j0 + (px & 3));
        float s = 1.0f;
        for (int k = kg; k < nh; k += 4) {
            int g = list[hbase + k];
            float4 g0 = *(const float4*)(gauss + ((size_t)g << 3));
            float4 g1 = *(const float4*)(gauss + ((size_t)g << 3) + 4);
            float a = eval_alpha(g0, g1, fi, fj);
            s *= (1.0f - a);
        }
        s *= __shfl_xor(s, 16, 64);
        s *= __shfl_xor(s, 32, 64);
        if (lane < 16) base[(size_t)e*16 + lane] = s;
    }
}

// per tile: exclusive MULTIPLICATIVE prefix of chunk products (in place)
__global__ __launch_bounds__(256) void chunk_prefix_kernel(const int* __restrict__ choff,
                                                           float* __restrict__ base) {
    __shared__ float part[16][17];
    const int tile = blockIdx.x, t = threadIdx.x;
    const int c0 = choff[tile], nch = choff[tile+1] - c0;
    if (nch == 0) return;
    const int px = t & 15, cg = t >> 4;
    const int L16 = (nch + 15) >> 4;
    const int a0 = cg*L16, a1 = min(nch, a0 + L16);
    float s = 1.0f;
    for (int c = a0; c < a1; ++c) s *= base[(size_t)(c0 + c)*16 + px];
    part[cg][px] = s;
    __syncthreads();
    if (t < 16) {
        float run = 1.0f;
        #pragma unroll
        for (int k = 0; k < 16; ++k) { float tmp = part[k][t]; part[k][t] = run; run *= tmp; }
    }
    __syncthreads();
    float run = part[cg][px];
    for (int c = a0; c < a1; ++c) {
        size_t idx = (size_t)(c0 + c)*16 + px;
        float tmp = base[idx];
        base[idx] = run;
        run *= tmp;
    }
}

// composite v12 (frozen): MFMA phase A, 2 chunks per barrier pair.
__global__ __launch_bounds__(256) void composite_kernel(const float* __restrict__ gauss,
        const unsigned short* __restrict__ colors16, const unsigned short* __restrict__ list,
        const int* __restrict__ cnt, const int* __restrict__ off, const int* __restrict__ wl,
        const int* __restrict__ nwork, const float* __restrict__ base, float* __restrict__ out) {
    const int nw = nwork[0];
    const int t = threadIdx.x;
    const int lane = t & 63;
    const int e_px = t >> 4, e_kg = t & 15;      // eval mapping
    const int wv_id = t >> 6;                    // wave 0..3 -> ch base wv_id*32
    const int m16 = lane & 15;                   // MFMA m/n lane index
    const int kb  = lane >> 4;                   // MFMA k-block 0..3
    const int chA = (wv_id << 5) + m16;          // N-block A channel
    const int chB = chA + 16;                    // N-block B channel
    const int f_pxq = t >> 5;                    // flush reader role (v2 pattern)
    const int f_r0  = f_pxq >> 2, f_j = f_pxq & 3;
    const int cs4r  = t & 31;
    __shared__ unsigned short slist[4][CSIZE];   // 4-deep ring
    __shared__ unsigned short s_w16[2][8][17][8]; // per-pair-slot bf16 weights
    __shared__ float fred[128*17];               // flush redistribution (8.5 KB)
    const int per = (nw + CBLK - 1) / CBLK;
    int e0 = blockIdx.x * per;
    if (e0 >= nw) return;
    int e1 = min(nw, e0 + per);

    f32x4 accA = {0.f,0.f,0.f,0.f};
    f32x4 accB = {0.f,0.f,0.f,0.f};
    int cur_tile = wl[e0] >> 9;
    int cur_i0 = (cur_tile / NTILE) * 4, cur_j0 = (cur_tile % NTILE) * 4;

    // prologue: load slists for e0 and e0+1 (zero-padded tails)
    int L = e0;
    for (; L < e1 && L < e0 + 2; ++L) {
        int v = wl[L], tl = v >> 9, c = v & 511;
        int nhl = min(CSIZE, cnt[tl] - (c << 6));
        if (t < CSIZE) slist[L & 3][t] = (t < nhl) ? list[off[tl] + (c << 6) + t] : 0;
    }

    int e = e0;
    while (e < e1) {
        int v = wl[e], tile = v >> 9, c = v & 511;
        bool pair = false; int c2 = 0;
        if (e + 1 < e1) {
            int v2 = wl[e+1];
            if ((v2 >> 9) == tile) { pair = true; c2 = v2 & 511; }
        }
        const bool tflush = (tile != cur_tile);
        const int fi0 = cur_i0, fj0 = cur_j0;    // capture OLD tile coords
        if (tflush) {
            const int cs4A = (wv_id << 3) + (m16 >> 2);
            const int compA = m16 & 3;
            #pragma unroll
            for (int r = 0; r < 4; ++r) {
                fred[((kb << 5) + cs4A)*17 + (r << 2) + compA]     = accA[r];
                fred[((kb << 5) + cs4A + 4)*17 + (r << 2) + compA] = accB[r];
            }
            accA = (f32x4){0.f,0.f,0.f,0.f};
            accB = (f32x4){0.f,0.f,0.f,0.f};
            cur_tile = tile;
            cur_i0 = (tile / NTILE) * 4; cur_j0 = (tile % NTILE) * 4;
        }
        const int nh  = min(CSIZE, cnt[tile] - (c << 6));
        const int nh2 = pair ? min(CSIZE, cnt[tile] - (c2 << 6)) : 0;
        __syncthreads();   // slists ready; prev s_w16 reads done; fred visible
        if (tflush) {
            const float* f0 = &fred[(f_r0*32 + cs4r)*17 + (f_j<<2)];
            const float* f1 = &fred[((f_r0+2)*32 + cs4r)*17 + (f_j<<2)];
            const int pix0 = (fi0 + f_r0) * BEVW + fj0 + f_j;
            const int pix1 = pix0 + 2 * BEVW;
            float* op = out + (size_t)(cs4r << 2) * NPXB;
            atomicAdd(op + 0*NPXB + pix0, f0[0]); atomicAdd(op + 1*NPXB + pix0, f0[1]);
            atomicAdd(op + 2*NPXB + pix0, f0[2]); atomicAdd(op + 3*NPXB + pix0, f0[3]);
            atomicAdd(op + 0*NPXB + pix1, f1[0]); atomicAdd(op + 1*NPXB + pix1, f1[1]);
            atomicAdd(op + 2*NPXB + pix1, f1[2]); atomicAdd(op + 3*NPXB + pix1, f1[3]);
        }
        {
            const int target = min(e1, e + (pair ? 2 : 1) + 2);
            for (; L < target; ++L) {
                int vv = wl[L], tl = vv >> 9, cc = vv & 511;
                int nhl = min(CSIZE, cnt[tl] - (cc << 6));
                if (t < CSIZE) slist[L & 3][t] = (t < nhl) ? list[off[tl] + (cc << 6) + t] : 0;
            }
        }
        // ---- phase E (both chunks): eval + interleaved product scans ----
        {
            const float fi = (float)(cur_i0 + (e_px >> 2)), fj = (float)(cur_j0 + (e_px & 3));
            const int k0 = e_kg << 2;
            float a4a[4], a4b[4];
            float p1 = 1.0f, p2 = 1.0f;
            #pragma unroll
            for (int i = 0; i < 4; ++i) {
                int k = k0 + i;
                float aa = 0.0f, ab = 0.0f;
                if (k < nh) {
                    int g = slist[e & 3][k];
                    float4 g0 = *(const float4*)(gauss + ((size_t)g << 3));
                    float4 g1 = *(const float4*)(gauss + ((size_t)g << 3) + 4);
                    aa = eval_alpha(g0, g1, fi, fj);
                }
                if (k < nh2) {
                    int g = slist[(e+1) & 3][k];
                    float4 g0 = *(const float4*)(gauss + ((size_t)g << 3));
                    float4 g1 = *(const float4*)(gauss + ((size_t)g << 3) + 4);
                    ab = eval_alpha(g0, g1, fi, fj);
                }
                a4a[i] = aa; a4b[i] = ab;
                p1 *= (1.0f - aa);
                p2 *= (1.0f - ab);
            }
            float sa = p1, sb = p2;
            #pragma unroll
            for (int o = 1; o < 16; o <<= 1) {
                float ua = __shfl_up(sa, (unsigned)o, 64);
                float ub = __shfl_up(sb, (unsigned)o, 64);
                if ((lane & 15) >= o) { sa *= ua; sb *= ub; }
            }
            float exa = __shfl_up(sa, 1u, 64);
            float exb = __shfl_up(sb, 1u, 64);
            const bool l0 = ((lane & 15) == 0);
            float Ta = base[(size_t)e*16 + e_px] * (l0 ? 1.0f : exa);
            unsigned short* swpa = &s_w16[0][e_kg >> 1][e_px][(e_kg & 1) << 2];
            #pragma unroll
            for (int i = 0; i < 4; ++i) {
                float wv_ = a4a[i] * Ta; Ta -= wv_;
                swpa[i] = f2bf(wv_);
            }
            if (pair) {
                float Tb = base[(size_t)(e+1)*16 + e_px] * (l0 ? 1.0f : exb);
                unsigned short* swpb = &s_w16[1][e_kg >> 1][e_px][(e_kg & 1) << 2];
                #pragma unroll
                for (int i = 0; i < 4; ++i) {
                    float wv_ = a4b[i] * Tb; Tb -= wv_;
                    swpb[i] = f2bf(wv_);
                }
            }
        }
        __syncthreads();   // s_w16 ready
        // ---- phase A: 4 (or 8) MFMA per wave; all B-gathers issued together ----
        {
            bf16x8 af0 = *(const bf16x8*)&s_w16[0][kb][m16][0];
            bf16x8 af1 = *(const bf16x8*)&s_w16[0][4 + kb][m16][0];
            bf16x8 bA0, bB0, bA1, bB1;
            #pragma unroll
            for (int j = 0; j < 8; ++j) {
                int g0i = slist[e & 3][(kb << 3) + j];
                int g1i = slist[e & 3][32 + (kb << 3) + j];
                const unsigned short* cp0 = colors16 + ((size_t)g0i << 7);
                const unsigned short* cp1 = colors16 + ((size_t)g1i << 7);
                bA0[j] = (short)cp0[chA]; bB0[j] = (short)cp0[chB];
                bA1[j] = (short)cp1[chA]; bB1[j] = (short)cp1[chB];
            }
            if (pair) {
                bf16x8 cf0 = *(const bf16x8*)&s_w16[1][kb][m16][0];
                bf16x8 cf1 = *(const bf16x8*)&s_w16[1][4 + kb][m16][0];
                bf16x8 dA0, dB0, dA1, dB1;
                #pragma unroll
                for (int j = 0; j < 8; ++j) {
                    int g0i = slist[(e+1) & 3][(kb << 3) + j];
                    int g1i = slist[(e+1) & 3][32 + (kb << 3) + j];
                    const unsigned short* cp0 = colors16 + ((size_t)g0i << 7);
                    const unsigned short* cp1 = colors16 + ((size_t)g1i << 7);
                    dA0[j] = (short)cp0[chA]; dB0[j] = (short)cp0[chB];
                    dA1[j] = (short)cp1[chA]; dB1[j] = (short)cp1[chB];
                }
                accA = __builtin_amdgcn_mfma_f32_16x16x32_bf16(af0, bA0, accA, 0, 0, 0);
                accB = __builtin_amdgcn_mfma_f32_16x16x32_bf16(af0, bB0, accB, 0, 0, 0);
                accA = __builtin_amdgcn_mfma_f32_16x16x32_bf16(af1, bA1, accA, 0, 0, 0);
                accB = __builtin_amdgcn_mfma_f32_16x16x32_bf16(af1, bB1, accB, 0, 0, 0);
                accA = __builtin_amdgcn_mfma_f32_16x16x32_bf16(cf0, dA0, accA, 0, 0, 0);
                accB = __builtin_amdgcn_mfma_f32_16x16x32_bf16(cf0, dB0, accB, 0, 0, 0);
                accA = __builtin_amdgcn_mfma_f32_16x16x32_bf16(cf1, dA1, accA, 0, 0, 0);
                accB = __builtin_amdgcn_mfma_f32_16x16x32_bf16(cf1, dB1, accB, 0, 0, 0);
            } else {
                accA = __builtin_amdgcn_mfma_f32_16x16x32_bf16(af0, bA0, accA, 0, 0, 0);
                accB = __builtin_amdgcn_mfma_f32_16x16x32_bf16(af0, bB0, accB, 0, 0, 0);
                accA = __builtin_amdgcn_mfma_f32_16x16x32_bf16(af1, bA1, accA, 0, 0, 0);
                accB = __builtin_amdgcn_mfma_f32_16x16x32_bf16(af1, bB1, accB, 0, 0, 0);
            }
        }
        e += pair ? 2 : 1;
    }
    // ---- final flush ----
    {
        const int cs4A = (wv_id << 3) + (m16 >> 2);
        const int compA = m16 & 3;
        #pragma unroll
        for (int r = 0; r < 4; ++r) {
            fred[((kb << 5) + cs4A)*17 + (r << 2) + compA]     = accA[r];
            fred[((kb << 5) + cs4A + 4)*17 + (r << 2) + compA] = accB[r];
        }
    }
    __syncthreads();
    {
        const float* f0 = &fred[(f_r0*32 + cs4r)*17 + (f_j<<2)];
        const float* f1 = &fred[((f_r0+2)*32 + cs4r)*17 + (f_j<<2)];
        const int pix0 = (cur_i0 + f_r0) * BEVW + cur_j0 + f_j;
        const int pix1 = pix0 + 2 * BEVW;
        float* op = out + (size_t)(cs4r << 2) * NPXB;
        atomicAdd(op + 0*NPXB + pix0, f0[0]); atomicAdd(op + 1*NPXB + pix0, f0[1]);
        atomicAdd(op + 2*NPXB + pix0, f0[2]); atomicAdd(op + 3*NPXB + pix0, f0[3]);
        atomicAdd(op + 0*NPXB + pix1, f1[0]); atomicAdd(op + 1*NPXB + pix1, f1[1]);
        atomicAdd(op + 2*NPXB + pix1, f1[2]); atomicAdd(op + 3*NPXB + pix1, f1[3]);
    }
}

extern "C" void kernel_launch(void* const* d_in, const int* in_sizes, int n_in,
                              void* d_out, int out_size, void* d_ws, size_t ws_size,
                              hipStream_t stream) {
    const float* rot  = (const float*)d_in[0];
    const float* tr   = (const float*)d_in[1];
    const float* intr = (const float*)d_in[2];
    const float* prot = (const float*)d_in[3];
    const float* ptr_ = (const float*)d_in[4];
    const float* img  = (const float*)d_in[5];
    const float* c1w  = (const float*)d_in[6];  const float* c1b = (const float*)d_in[7];
    const float* b1g  = (const float*)d_in[8];  const float* b1b = (const float*)d_in[9];
    const float* b1m  = (const float*)d_in[10]; const float* b1v = (const float*)d_in[11];
    const float* c2w  = (const float*)d_in[12]; const float* c2b = (const float*)d_in[13];
    const float* b2g  = (const float*)d_in[14]; const float* b2b = (const float*)d_in[15];
    const float* b2m  = (const float*)d_in[16]; const float* b2v = (const float*)d_in[17];
    const float* c3w  = (const float*)d_in[18]; const float* c3b = (const float*)d_in[19];
    float* out = (float*)d_out;
    float* ws  = (float*)d_ws;
    unsigned short* PAD16 = (unsigned short*)(ws + WS_A);          // also conv2out16
    unsigned short* C1O16 = (unsigned short*)(ws + WS_A + C1OFF);
    unsigned short* COL16 = (unsigned short*)(ws + WS_RB);
    float* X3B = ws + WS_X3;
    unsigned short* WC1 = (unsigned short*)X3B;                    // dead until conv1x1
    unsigned short* WC2 = WC1 + WELEM;
    float* GS  = ws + WS_GS;
    int*   WL  = (int*)(ws + WS_WL);
    float* BASE = ws + WS_BASE;
    unsigned long long* MASKS = (unsigned long long*)BASE;
    int* AUXI = (int*)(ws + WS_X3 + 330000);
    int* CNT = AUXI;           // 625
    int* OFF = AUXI + 640;     // 626
    int* CHOFF = AUXI + 1280;  // 626
    int* NWORK = AUXI + 1920;  // 1
    unsigned short* LIST = (unsigned short*)(ws + WS_A);           // after convs dead
    float* ngp = out + (size_t)NPXB*OUTC;

    prep_weights_kernel<<<(2*WELEM + 255)/256, 256, 0, stream>>>(c1w, c2w, WC1, WC2);
    pad_tr_kernel<<<NCAM*PH, 256, 0, stream>>>(img, PAD16, C1O16, out, MASKS);
    conv3x3_mfma_kernel<<<dim3(NCAM,64,4), 128, 0, stream>>>(PAD16, C1O16, WC1,
                                                             c1b, b1g, b1b, b1m, b1v);
    conv3x3_mfma_kernel<<<dim3(NCAM,64,4), 128, 0, stream>>>(C1O16, PAD16, WC2,
                                                             c2b, b2g, b2b, b2m, b2v);
    conv1x1_kernel<<<dim3(NCAM,11,22), 256, 0, stream>>>(PAD16, X3B, COL16, c3w, c3b);
    moments_kernel<<<GTOT/256, 256, 0, stream>>>(X3B, rot, tr, intr, prot, ptr_, GS, ngp);
    scatter_masks_kernel<<<GTOT*4/256, 256, 0, stream>>>(GS, MASKS);
    cnt_kernel<<<NTILE*NTILE, 256, 0, stream>>>(MASKS, CNT);
    scan_kernel<<<1, 640, 0, stream>>>(CNT, OFF, CHOFF, NWORK);
    fill_kernel<<<NTILE*NTILE, 256, 0, stream>>>(MASKS, CNT, OFF, CHOFF, LIST, WL);
    chunk_sums_kernel<<<8192, 256, 0, stream>>>(GS, LIST, CNT, OFF, WL, NWORK, BASE);
    chunk_prefix_kernel<<<NTILE*NTILE, 256, 0, stream>>>(CHOFF, BASE);
    composite_kernel<<<CBLK, 256, 0, stream>>>(GS, COL16, LIST, CNT, OFF, WL, NWORK, BASE, out);
}

// Round 18
// 396.580 us; speedup vs baseline: 1.0032x; 1.0032x over previous
//
#include <hip/hip_runtime.h>

#define NCAM 6
#define FC   128
#define FH_  32
#define FW_  88
#define NPIX (FH_*FW_)        // 2816
#define PH   34
#define PW   92               // padded width
#define PPIX (PH*PW)          // 3128
#define ND   41
#define X3D  42               // 41 depth + 1 opacity planes
#define OUTC 128
#define GTOT (NCAM*NPIX)      // 16896
#define BEVH 100
#define BEVW 100
#define NPXB (BEVH*BEVW)      // 10000
#define NTILE 25              // 25x25 tiles of 4x4 px
#define NWORD 264             // 16896/64 mask words per tile
#define NMASKW (NTILE*NTILE*NWORD)  // 165000 u64
#define WCAP  70000           // worklist capacity (chunks)
#define CSIZE 64              // hits per chunk
#define CBLK  2048            // composite blocks (contiguous chunk ranges)

// ---- ws layout (float offsets). ----
#define SZA     (NCAM*FC*PPIX)           // 2402304
#define WS_A    256
#define C1OFF   1201152                   // float offset of conv1out16
#define WS_RB   (WS_A  + SZA)            // colors16 (bf16) lives here
#define WS_X3   (WS_RB + SZA)            // wcvt (early) -> x3d fp32 -> aux ints
#define WS_GS   (WS_X3 + NCAM*X3D*NPIX)  // gauss params 16896*8
#define WS_WL   (WS_GS + GTOT*8)         // worklist ints
#define WS_BASE (WS_WL + WCAP)           // MASKS (early) then per-chunk bases (late)
#define WELEM   (9*128*128)              // 147456 elems per wcvt array

typedef __attribute__((ext_vector_type(8))) short bf16x8;
typedef __attribute__((ext_vector_type(4))) float f32x4;

__device__ inline unsigned short f2bf(float f) {
    unsigned u = __float_as_uint(f);
    u += 0x7fffu + ((u >> 16) & 1u);     // round-to-nearest-even
    return (unsigned short)(u >> 16);
}
__device__ inline float bf2f(unsigned short h) {
    unsigned u = ((unsigned)h) << 16;
    return __uint_as_float(u);
}

__device__ inline void inv3x3(const float* m, float* o) {
    float a=m[0],b=m[1],c=m[2],d=m[3],e=m[4],f=m[5],g=m[6],h=m[7],i=m[8];
    float A=e*i-f*h, B=c*h-b*i, C=b*f-c*e;
    float Dd=f*g-d*i, E=a*i-c*g, F=c*d-a*f;
    float Gg=d*h-e*g, H=b*g-a*h, I=a*e-b*d;
    float r = 1.0f/(a*A + b*Dd + c*Gg);
    o[0]=A*r; o[1]=B*r; o[2]=C*r; o[3]=Dd*r; o[4]=E*r; o[5]=F*r;
    o[6]=Gg*r; o[7]=H*r; o[8]=I*r;
}

// convert conv weights fp32 [co][ci][3][3] -> bf16 [tap][co][ci] (both layers)
__global__ __launch_bounds__(256) void prep_weights_kernel(const float* __restrict__ w1,
        const float* __restrict__ w2, unsigned short* __restrict__ wc1,
        unsigned short* __restrict__ wc2) {
    int idx = blockIdx.x*256 + threadIdx.x;
    if (idx >= 2*WELEM) return;
    const float* src = (idx < WELEM) ? w1 : w2;
    unsigned short* dst = (idx < WELEM) ? wc1 : wc2;
    int e = (idx < WELEM) ? idx : idx - WELEM;
    int tap = e / (128*128), r = e - tap*(128*128);
    int co = r >> 7, ci = r & 127;
    int dy = tap / 3, dx = tap - dy*3;
    dst[e] = f2bf(src[((co*128 + ci)*3 + dy)*3 + dx]);
}

// transpose-pad: img fp32 [n][ci][y][x] -> pad16 bf16 [n][y][xp][ci] with zero
// borders; also zeros conv1out16 borders, out+ngp, MASKS (memset fold).
__global__ __launch_bounds__(256) void pad_tr_kernel(const float* __restrict__ src,
        unsigned short* __restrict__ pad16, unsigned short* __restrict__ c1o16,
        float* __restrict__ outp, unsigned long long* __restrict__ masks) {
    __shared__ unsigned short lds[92*132];
    const int bid = blockIdx.x;               // 0..203 = (n, y)
    const int n = bid / PH, y = bid - n*PH;
    const int t = threadIdx.x;
    // memset fold: out planes + ngp, masks
    for (int j = bid*256 + t; j <= NPXB*OUTC; j += 204*256) outp[j] = 0.0f;
    for (int j = bid*256 + t; j < NMASKW; j += 204*256) masks[j] = 0ull;

    unsigned short* prow = pad16 + ((size_t)n*PPIX + y*PW)*128;
    unsigned short* crow = c1o16 + ((size_t)n*PPIX + y*PW)*128;
    if (y == 0 || y == PH-1) {
        for (int j = t; j < PW*128; j += 256) { prow[j] = 0; crow[j] = 0; }
        return;
    }
    // zero border cols xp in {0,89,90,91} of lds, and of conv1out16 row
    for (int j = t; j < 4*128; j += 256) {
        int bc = j >> 7, ci = j & 127;
        int xp = (bc == 0) ? 0 : (88 + bc);
        lds[xp*132 + ci] = 0;
        crow[xp*128 + ci] = 0;
    }
    // read src row (y-1 in true coords), coalesced per ci-row; write lds[xp][ci]
    const float* sp = src + (size_t)n*FC*NPIX + (size_t)(y-1)*FW_;
    for (int j = t; j < 128*FW_; j += 256) {
        int ci = j / FW_, x = j - ci*FW_;
        lds[(x+1)*132 + ci] = f2bf(sp[(size_t)ci*NPIX + x]);
    }
    __syncthreads();
    // write pad16 row contiguously (ushort scalar stores, coalesced)
    for (int j = t; j < PW*128; j += 256) {
        int xp = j >> 7, ci = j & 127;
        prow[j] = lds[xp*132 + ci];
    }
}

// 3x3 conv as MFMA GEMM. v2 (BEST VERIFIED, R16 = 397.57us): M-split grid —
// blockIdx.y in [0,64): y-row = (by>>1)+1, m-half = by&1 covers 3 of 6 16-px
// column tiles. 768 blocks (3/CU), 256-thread blocks (4 waves).
__global__ __launch_bounds__(256) void conv3x3_mfma_kernel(
        const unsigned short* __restrict__ in16, unsigned short* __restrict__ out16,
        const unsigned short* __restrict__ wcvt,
        const float* __restrict__ cb, const float* __restrict__ bg,
        const float* __restrict__ bb, const float* __restrict__ bm,
        const float* __restrict__ bv) {
    const int n = blockIdx.x;
    const int y = (blockIdx.y >> 1) + 1;     // output padded row 1..32
    const int mh = blockIdx.y & 1;           // m-half: column tiles mh*3..mh*3+2
    const int half = blockIdx.z;             // co half
    const int t = threadIdx.x;
    const int lane = t & 63, wv = t >> 6;
    const int n16 = lane & 15, kb = lane >> 4;
    const int co = half*64 + wv*16 + n16;    // this lane's output channel
    const float scale = bg[co] * rsqrtf(bv[co] + 1e-3f);
    const float shift = (cb[co] - bm[co]) * scale + bb[co];

    const unsigned short* ibase = in16 + (size_t)n*PPIX*128;
    f32x4 acc[3];
    #pragma unroll
    for (int m = 0; m < 3; ++m) acc[m] = (f32x4){0.f,0.f,0.f,0.f};

    for (int kc = 0; kc < 4; ++kc) {
        #pragma unroll
        for (int tap = 0; tap < 9; ++tap) {
            const int dy = tap / 3, dx = tap - dy*3;
            bf16x8 bfrag = *(const bf16x8*)(wcvt + ((size_t)(tap*128 + co))*128 + kc*32 + kb*8);
            const unsigned short* arow = ibase + (size_t)(y + dy - 1)*PW*128 + kc*32 + kb*8;
            #pragma unroll
            for (int m = 0; m < 3; ++m) {
                int col = (mh*3 + m)*16 + n16 + dx;  // input padded col
                col = min(col, 91);
                bf16x8 afrag = *(const bf16x8*)(arow + (size_t)col*128);
                acc[m] = __builtin_amdgcn_mfma_f32_16x16x32_bf16(afrag, bfrag, acc[m], 0, 0, 0);
            }
        }
    }
    // epilogue: C row(px) = kb*4 + r, col = n16 -> store out16[y][xp][co]
    unsigned short* obase = out16 + ((size_t)n*PPIX + y*PW)*128 + co;
    #pragma unroll
    for (int m = 0; m < 3; ++m) {
        #pragma unroll
        for (int r = 0; r < 4; ++r) {
            int xp = 1 + (mh*3 + m)*16 + kb*4 + r;
            if (xp <= 88) {
                float v = fmaxf(fmaf(acc[m][r], scale, shift), 0.0f);
                obase[(size_t)xp*128] = f2bf(v);
            }
        }
    }
}

// 1x1 conv from bf16 TRANSPOSED input [n][pp][ci] (ci-contiguous per px).
__global__ __launch_bounds__(256) void conv1x1_kernel(const unsigned short* __restrict__ in16,
        float* __restrict__ x3d, unsigned short* __restrict__ colors16,
        const float* __restrict__ w, const float* __restrict__ b) {
    const int n   = blockIdx.x;
    const int px  = blockIdx.y * 256 + threadIdx.x;
    const int y   = px / FW_, x = px - y*FW_;
    const int pp  = (y+1)*PW + (x+1);
    const unsigned short* ip = in16 + ((size_t)n*PPIX + pp)*128;
    if (blockIdx.z < 6) {
        const int co0 = blockIdx.z * 7;
        const float* wr[7];
        float acc[7];
        #pragma unroll
        for (int k=0;k<7;k++) {
            int co = co0 + k;
            wr[k]  = w + (size_t)co*FC;
            acc[k] = b[co];
        }
        for (int c8 = 0; c8 < 16; ++c8) {
            uint4 pk = *(const uint4*)(ip + c8*8);
            const unsigned* pw = (const unsigned*)&pk;
            #pragma unroll
            for (int j = 0; j < 4; ++j) {
                float v0 = bf2f((unsigned short)(pw[j] & 0xffffu));
                float v1 = bf2f((unsigned short)(pw[j] >> 16));
                int ci = c8*8 + j*2;
                #pragma unroll
                for (int k=0;k<7;k++) {
                    acc[k] = fmaf(wr[k][ci],   v0, acc[k]);
                    acc[k] = fmaf(wr[k][ci+1], v1, acc[k]);
                }
            }
        }
        #pragma unroll
        for (int k=0;k<7;k++)
            x3d[((size_t)n*X3D + co0 + k)*NPIX + px] = acc[k];
    } else {
        const int c0  = (blockIdx.z - 6) * 8;
        const int co0 = X3D + c0;
        const float* wr[8];
        float acc[8];
        #pragma unroll
        for (int k=0;k<8;k++) {
            int co = co0 + k;
            wr[k]  = w + (size_t)co*FC;
            acc[k] = b[co];
        }
        for (int c8 = 0; c8 < 16; ++c8) {
            uint4 pk = *(const uint4*)(ip + c8*8);
            const unsigned* pw = (const unsigned*)&pk;
            #pragma unroll
            for (int j = 0; j < 4; ++j) {
                float v0 = bf2f((unsigned short)(pw[j] & 0xffffu));
                float v1 = bf2f((unsigned short)(pw[j] >> 16));
                int ci = c8*8 + j*2;
                #pragma unroll
                for (int k=0;k<8;k++) {
                    acc[k] = fmaf(wr[k][ci],   v0, acc[k]);
                    acc[k] = fmaf(wr[k][ci+1], v1, acc[k]);
                }
            }
        }
        unsigned short h[8];
        #pragma unroll
        for (int k=0;k<8;k++) h[k] = f2bf(acc[k]);
        uint4 pk;
        pk.x = (unsigned)h[0] | ((unsigned)h[1] << 16);
        pk.y = (unsigned)h[2] | ((unsigned)h[3] << 16);
        pk.z = (unsigned)h[4] | ((unsigned)h[5] << 16);
        pk.w = (unsigned)h[6] | ((unsigned)h[7] << 16);
        *(uint4*)(colors16 + (((size_t)(n*NPIX + px)) << 7) + c0) = pk;
    }
}

// cam consts (per-block LDS) + softmax moments + splat params. 66 blocks.
__global__ __launch_bounds__(256) void moments_kernel(const float* __restrict__ x3,
        const float* __restrict__ rot, const float* __restrict__ tr,
        const float* __restrict__ intr, const float* __restrict__ prot,
        const float* __restrict__ ptr_, float* __restrict__ gauss,
        float* __restrict__ ng) {
    __shared__ float cc[24];
    const int n = blockIdx.x / 11;
    if (threadIdx.x == 0) {
        float M1[9], Ki[9];
        inv3x3(prot + n*9, M1);
        inv3x3(intr + n*9, Ki);
        const float* R = rot + n*9;
        #pragma unroll
        for (int i=0;i<9;i++) cc[i] = M1[i];
        #pragma unroll
        for (int i=0;i<3;i++) cc[9+i] = ptr_[n*3+i];
        #pragma unroll
        for (int i=0;i<3;i++)
            #pragma unroll
            for (int j=0;j<3;j++)
                cc[12+i*3+j] = R[i*3+0]*Ki[0+j] + R[i*3+1]*Ki[3+j] + R[i*3+2]*Ki[6+j];
        #pragma unroll
        for (int i=0;i<3;i++) cc[21+i] = tr[n*3+i];
    }
    __syncthreads();
    const int gi = blockIdx.x*256 + threadIdx.x;
    const int p  = gi - n*NPIX;
    const int h  = p / FW_, xp = p - h*FW_;
    float u = xp * (703.0f/87.0f);
    float v = h  * (255.0f/31.0f);
    float fx = u - cc[9], fy = v - cc[10], fz = -cc[11];
    float p0x = cc[0]*fx + cc[1]*fy + cc[2]*fz;
    float p0y = cc[3]*fx + cc[4]*fy + cc[5]*fz;
    float p0z = cc[6]*fx + cc[7]*fy + cc[8]*fz;
    const float* lg = x3 + (size_t)n*X3D*NPIX + p;

    float lgv[ND];
    #pragma unroll
    for (int d=0; d<ND; ++d) lgv[d] = lg[(size_t)d*NPIX];

    float mxl = -1e30f;
    #pragma unroll
    for (int d=0; d<ND; ++d) mxl = fmaxf(mxl, lgv[d]);

    float s=0.f, sgx=0.f, sgy=0.f;
    #pragma unroll
    for (int d=0; d<ND; ++d) {
        float e  = __expf(lgv[d] - mxl);
        lgv[d] = e;
        float dz = 4.0f + (float)d;
        float pz = p0z + dz*cc[8];
        float px = (p0x + dz*cc[2]) * pz;
        float py = (p0y + dz*cc[5]) * pz;
        float gx = cc[12]*px + cc[13]*py + cc[14]*pz + cc[21];
        float gy = cc[15]*px + cc[16]*py + cc[17]*pz + cc[22];
        s += e; sgx += e*gx; sgy += e*gy;
    }
    float inv_s = 1.0f/s;
    float mex = sgx*inv_s, mey = sgy*inv_s;
    float cxx=0.f, cxy=0.f, cyy=0.f;
    #pragma unroll
    for (int d=0; d<ND; ++d) {
        float e  = lgv[d];
        float dz = 4.0f + (float)d;
        float pz = p0z + dz*cc[8];
        float px = (p0x + dz*cc[2]) * pz;
        float py = (p0y + dz*cc[5]) * pz;
        float gx = cc[12]*px + cc[13]*py + cc[14]*pz + cc[21];
        float gy = cc[15]*px + cc[16]*py + cc[17]*pz + cc[22];
        float dxv = gx - mex, dyv = gy - mey;
        cxx += e*dxv*dxv; cxy += e*dxv*dyv; cyy += e*dyv*dyv;
    }
    const float k9 = inv_s * (1.0f/9.0f);
    cxx *= k9; cxy *= k9; cyy *= k9;

    float lo = lg[(size_t)ND*NPIX];
    float op = 1.0f/(1.0f + __expf(-lo));
    bool mask = op > 0.05f;

    const float SC = 0.02f, SH = 50.0f, SW = 50.0f;
    float my = -SH*(mey*SC) + 50.0f;
    float mx = -SW*(mex*SC) + 50.0f;
    float a  = SH*SH*(cyy*SC*SC) + 0.3f;
    float b  = SH*SW*(cxy*SC*SC);
    float c  = SW*SW*(cxx*SC*SC) + 0.3f;
    float det = a*c - b*b;
    bool valid = mask && (det > 0.0f);
    float A, B2, C, qm, ri, rj;
    if (valid) {
        float idet = 1.0f/det;
        A = c*idet; B2 = -2.0f*b*idet; C = a*idet;
        qm = 2.0f*__logf(255.0f*op);
        ri = sqrtf(qm*a); rj = sqrtf(qm*c);
    } else { A=B2=C=0.f; qm=-1.0f; ri=-1e30f; rj=-1e30f; }
    float* gp = gauss + (size_t)gi*8;
    gp[0]=my; gp[1]=mx; gp[2]=A; gp[3]=B2; gp[4]=C; gp[5]=qm; gp[6]=ri; gp[7]=rj;

    unsigned long long bal = __ballot(mask);
    if ((threadIdx.x & 63) == 0) atomicAdd(ng, (float)__popcll(bal));
}

// tile bitmask scatter, 4x parallel: thread = (gaussian, ti-quarter).
__global__ __launch_bounds__(256) void scatter_masks_kernel(const float* __restrict__ gauss,
        unsigned long long* __restrict__ masks) {
    const int idx = blockIdx.x*256 + threadIdx.x;    // 0..67583
    const int g = idx >> 2, q = idx & 3;
    const float4 g0 = *(const float4*)(gauss + ((size_t)g << 3));      // my,mx,A,2B
    const float4 g1 = *(const float4*)(gauss + ((size_t)g << 3) + 4);  // C,qm,ri,rj
    if (g1.y < 0.0f) return;
    const float my = g0.x, mx = g0.y, A = g0.z, B = 0.5f*g0.w, C = g1.x, qm = g1.y, ri = g1.z;
    const float invC = 1.0f / C;
    const float k2 = C*A - B*B;          // > 0
    int ti0 = max(0, (int)floorf((my - ri) * 0.25f));
    int ti1 = min(NTILE-1, (int)floorf((my + ri) * 0.25f));
    int len = ti1 - ti0 + 1;
    int ta = ti0 + (len*q) / 4;
    int tb = ti0 + (len*(q+1)) / 4;      // disjoint union over q=0..3
    const int wi = g >> 6;
    const unsigned long long bit = 1ull << (g & 63);
    for (int ti = ta; ti < tb; ++ti) {
        float jmn = 1e30f, jmx = -1e30f;
        #pragma unroll
        for (int r = 0; r < 4; ++r) {
            int i = 4*ti + r;
            if (i < 0 || i > 99) continue;
            float di = (float)i - my;
            float disc = C*qm - k2*di*di;
            if (disc < 0.0f) continue;
            float sd = sqrtf(disc);
            float jc = -B*di;
            jmn = fminf(jmn, (jc - sd)*invC + mx);
            jmx = fmaxf(jmx, (jc + sd)*invC + mx);
        }
        if (jmx < jmn) continue;
        int jl = max(0, (int)ceilf(jmn));
        int jh = min(99, (int)floorf(jmx));
        if (jl > jh) continue;
        for (int tj = (jl >> 2); tj <= (jh >> 2); ++tj)
            atomicOr(&masks[(size_t)(ti*NTILE + tj)*NWORD + wi], bit);
    }
}

// per-tile hit count
__global__ __launch_bounds__(256) void cnt_kernel(const unsigned long long* __restrict__ masks,
                                                  int* __restrict__ cnt) {
    __shared__ int sc;
    const int tile = blockIdx.x, t = threadIdx.x;
    if (t == 0) sc = 0;
    __syncthreads();
    if (t < NWORD) atomicAdd(&sc, __popcll(masks[(size_t)tile*NWORD + t]));
    __syncthreads();
    if (t == 0) cnt[tile] = sc;
}

// parallel exclusive scans over 625 tiles (single 640-thread block, shfl scan)
__global__ __launch_bounds__(640) void scan_kernel(const int* __restrict__ cnt,
        int* __restrict__ off, int* __restrict__ choff, int* __restrict__ nwork) {
    __shared__ int wsum[16], wsum2[16];
    const int t = threadIdx.x;
    const int lane = t & 63, wv = t >> 6;
    int c  = (t < NTILE*NTILE) ? cnt[t] : 0;
    int ch = (c + CSIZE-1) >> 6;
    int v = c, v2 = ch;
    #pragma unroll
    for (int o = 1; o < 64; o <<= 1) {
        int u  = __shfl_up(v,  (unsigned)o, 64);
        int u2 = __shfl_up(v2, (unsigned)o, 64);
        if (lane >= o) { v += u; v2 += u2; }
    }
    if (lane == 63) { wsum[wv] = v; wsum2[wv] = v2; }
    __syncthreads();
    int pre = 0, pre2 = 0;
    for (int w2 = 0; w2 < wv; ++w2) { pre += wsum[w2]; pre2 += wsum2[w2]; }
    int inc = v + pre, inc2 = v2 + pre2;
    if (t < NTILE*NTILE) { off[t] = inc - c; choff[t] = inc2 - ch; }
    if (t == NTILE*NTILE - 1) {
        off[NTILE*NTILE] = inc;
        choff[NTILE*NTILE] = inc2;
        nwork[0] = (inc2 > WCAP) ? WCAP : inc2;
    }
}

// expand bitmasks -> dense ordered hit lists + chunk worklist
__global__ __launch_bounds__(256) void fill_kernel(const unsigned long long* __restrict__ masks,
        const int* __restrict__ cnt, const int* __restrict__ off, const int* __restrict__ choff,
        unsigned short* __restrict__ list, int* __restrict__ wl) {
    __shared__ unsigned long long sw[NWORD];
    __shared__ int wpre[NWORD];
    const int tile = blockIdx.x, t = threadIdx.x;
    if (t < NWORD) sw[t] = masks[(size_t)tile*NWORD + t];
    __syncthreads();
    if (t == 0) {
        int run = 0;
        for (int w2 = 0; w2 < NWORD; ++w2) { wpre[w2] = run; run += __popcll(sw[w2]); }
    }
    __syncthreads();
    if (t < NWORD) {
        unsigned long long m = sw[t];
        int pos = off[tile] + wpre[t], base = t << 6;
        while (m) { int b = __builtin_ctzll(m); m &= m - 1; list[pos++] = (unsigned short)(base + b); }
    }
    int nch = (cnt[tile] + CSIZE-1)/CSIZE;
    int c0 = choff[tile];
    if (t < nch && c0 + t < WCAP) wl[c0 + t] = (tile << 9) | t;
}

__device__ inline float eval_alpha(const float4 g0, const float4 g1, float fi, float fj) {
    float dI = fi - g0.x, dJ = fj - g0.y;
    float q = dI*(g0.z*dI + g0.w*dJ) + g1.x*dJ*dJ;     // g0.w = 2B
    if (q < 0.0f || q > g1.y) return 0.0f;
    return fminf(0.99f, 0.003921568627f * __expf(0.5f*(g1.y - q)));
}

// per chunk: per-px PRODUCT of (1-alpha) -> BASE[e][px] (pre-prefix).
__global__ __launch_bounds__(256) void chunk_sums_kernel(const float* __restrict__ gauss,
        const unsigned short* __restrict__ list, const int* __restrict__ cnt,
        const int* __restrict__ off, const int* __restrict__ wl, const int* __restrict__ nwork,
        float* __restrict__ base) {
    const int nw = nwork[0];
    const int lane = threadIdx.x & 63;
    const int wid  = (blockIdx.x * 256 + threadIdx.x) >> 6;   // global wave id
    const int nwv  = (gridDim.x * 256) >> 6;
    const int px = lane & 15, kg = lane >> 4;
    for (int e = wid; e < nw; e += nwv) {
        int v = wl[e], tile = v >> 9, c = v & 511;
        int hbase = off[tile] + (c << 6);
        int nh = min(CSIZE, cnt[tile] - (c << 6));
        const int i0 = (tile / NTILE) * 4, j0 = (tile % NTILE) * 4;
        const float fi = (float)(i0 + (px >> 2)), fj = (float)(j0 + (px & 3));
        float s = 1.0f;
        for (int k = kg; k < nh; k += 4) {
            int g = list[hbase + k];
            float4 g0 = *(const float4*)(gauss + ((size_t)g << 3));
            float4 g1 = *(const float4*)(gauss + ((size_t)g << 3) + 4);
            float a = eval_alpha(g0, g1, fi, fj);
            s *= (1.0f - a);
        }
        s *= __shfl_xor(s, 16, 64);
        s *= __shfl_xor(s, 32, 64);
        if (lane < 16) base[(size_t)e*16 + lane] = s;
    }
}

// per tile: exclusive MULTIPLICATIVE prefix of chunk products (in place)
__global__ __launch_bounds__(256) void chunk_prefix_kernel(const int* __restrict__ choff,
                                                           float* __restrict__ base) {
    __shared__ float part[16][17];
    const int tile = blockIdx.x, t = threadIdx.x;
    const int c0 = choff[tile], nch = choff[tile+1] - c0;
    if (nch == 0) return;
    const int px = t & 15, cg = t >> 4;
    const int L16 = (nch + 15) >> 4;
    const int a0 = cg*L16, a1 = min(nch, a0 + L16);
    float s = 1.0f;
    for (int c = a0; c < a1; ++c) s *= base[(size_t)(c0 + c)*16 + px];
    part[cg][px] = s;
    __syncthreads();
    if (t < 16) {
        float run = 1.0f;
        #pragma unroll
        for (int k = 0; k < 16; ++k) { float tmp = part[k][t]; part[k][t] = run; run *= tmp; }
    }
    __syncthreads();
    float run = part[cg][px];
    for (int c = a0; c < a1; ++c) {
        size_t idx = (size_t)(c0 + c)*16 + px;
        float tmp = base[idx];
        base[idx] = run;
        run *= tmp;
    }
}

// composite v12 (frozen): MFMA phase A, 2 chunks per barrier pair.
__global__ __launch_bounds__(256) void composite_kernel(const float* __restrict__ gauss,
        const unsigned short* __restrict__ colors16, const unsigned short* __restrict__ list,
        const int* __restrict__ cnt, const int* __restrict__ off, const int* __restrict__ wl,
        const int* __restrict__ nwork, const float* __restrict__ base, float* __restrict__ out) {
    const int nw = nwork[0];
    const int t = threadIdx.x;
    const int lane = t & 63;
    const int e_px = t >> 4, e_kg = t & 15;      // eval mapping
    const int wv_id = t >> 6;                    // wave 0..3 -> ch base wv_id*32
    const int m16 = lane & 15;                   // MFMA m/n lane index
    const int kb  = lane >> 4;                   // MFMA k-block 0..3
    const int chA = (wv_id << 5) + m16;          // N-block A channel
    const int chB = chA + 16;                    // N-block B channel
    const int f_pxq = t >> 5;                    // flush reader role (v2 pattern)
    const int f_r0  = f_pxq >> 2, f_j = f_pxq & 3;
    const int cs4r  = t & 31;
    __shared__ unsigned short slist[4][CSIZE];   // 4-deep ring
    __shared__ unsigned short s_w16[2][8][17][8]; // per-pair-slot bf16 weights
    __shared__ float fred[128*17];               // flush redistribution (8.5 KB)
    const int per = (nw + CBLK - 1) / CBLK;
    int e0 = blockIdx.x * per;
    if (e0 >= nw) return;
    int e1 = min(nw, e0 + per);

    f32x4 accA = {0.f,0.f,0.f,0.f};
    f32x4 accB = {0.f,0.f,0.f,0.f};
    int cur_tile = wl[e0] >> 9;
    int cur_i0 = (cur_tile / NTILE) * 4, cur_j0 = (cur_tile % NTILE) * 4;

    // prologue: load slists for e0 and e0+1 (zero-padded tails)
    int L = e0;
    for (; L < e1 && L < e0 + 2; ++L) {
        int v = wl[L], tl = v >> 9, c = v & 511;
        int nhl = min(CSIZE, cnt[tl] - (c << 6));
        if (t < CSIZE) slist[L & 3][t] = (t < nhl) ? list[off[tl] + (c << 6) + t] : 0;
    }

    int e = e0;
    while (e < e1) {
        int v = wl[e], tile = v >> 9, c = v & 511;
        bool pair = false; int c2 = 0;
        if (e + 1 < e1) {
            int v2 = wl[e+1];
            if ((v2 >> 9) == tile) { pair = true; c2 = v2 & 511; }
        }
        const bool tflush = (tile != cur_tile);
        const int fi0 = cur_i0, fj0 = cur_j0;    // capture OLD tile coords
        if (tflush) {
            const int cs4A = (wv_id << 3) + (m16 >> 2);
            const int compA = m16 & 3;
            #pragma unroll
            for (int r = 0; r < 4; ++r) {
                fred[((kb << 5) + cs4A)*17 + (r << 2) + compA]     = accA[r];
                fred[((kb << 5) + cs4A + 4)*17 + (r << 2) + compA] = accB[r];
            }
            accA = (f32x4){0.f,0.f,0.f,0.f};
            accB = (f32x4){0.f,0.f,0.f,0.f};
            cur_tile = tile;
            cur_i0 = (tile / NTILE) * 4; cur_j0 = (tile % NTILE) * 4;
        }
        const int nh  = min(CSIZE, cnt[tile] - (c << 6));
        const int nh2 = pair ? min(CSIZE, cnt[tile] - (c2 << 6)) : 0;
        __syncthreads();   // slists ready; prev s_w16 reads done; fred visible
        if (tflush) {
            const float* f0 = &fred[(f_r0*32 + cs4r)*17 + (f_j<<2)];
            const float* f1 = &fred[((f_r0+2)*32 + cs4r)*17 + (f_j<<2)];
            const int pix0 = (fi0 + f_r0) * BEVW + fj0 + f_j;
            const int pix1 = pix0 + 2 * BEVW;
            float* op = out + (size_t)(cs4r << 2) * NPXB;
            atomicAdd(op + 0*NPXB + pix0, f0[0]); atomicAdd(op + 1*NPXB + pix0, f0[1]);
            atomicAdd(op + 2*NPXB + pix0, f0[2]); atomicAdd(op + 3*NPXB + pix0, f0[3]);
            atomicAdd(op + 0*NPXB + pix1, f1[0]); atomicAdd(op + 1*NPXB + pix1, f1[1]);
            atomicAdd(op + 2*NPXB + pix1, f1[2]); atomicAdd(op + 3*NPXB + pix1, f1[3]);
        }
        {
            const int target = min(e1, e + (pair ? 2 : 1) + 2);
            for (; L < target; ++L) {
                int vv = wl[L], tl = vv >> 9, cc = vv & 511;
                int nhl = min(CSIZE, cnt[tl] - (cc << 6));
                if (t < CSIZE) slist[L & 3][t] = (t < nhl) ? list[off[tl] + (cc << 6) + t] : 0;
            }
        }
        // ---- phase E (both chunks): eval + interleaved product scans ----
        {
            const float fi = (float)(cur_i0 + (e_px >> 2)), fj = (float)(cur_j0 + (e_px & 3));
            const int k0 = e_kg << 2;
            float a4a[4], a4b[4];
            float p1 = 1.0f, p2 = 1.0f;
            #pragma unroll
            for (int i = 0; i < 4; ++i) {
                int k = k0 + i;
                float aa = 0.0f, ab = 0.0f;
                if (k < nh) {
                    int g = slist[e & 3][k];
                    float4 g0 = *(const float4*)(gauss + ((size_t)g << 3));
                    float4 g1 = *(const float4*)(gauss + ((size_t)g << 3) + 4);
                    aa = eval_alpha(g0, g1, fi, fj);
                }
                if (k < nh2) {
                    int g = slist[(e+1) & 3][k];
                    float4 g0 = *(const float4*)(gauss + ((size_t)g << 3));
                    float4 g1 = *(const float4*)(gauss + ((size_t)g << 3) + 4);
                    ab = eval_alpha(g0, g1, fi, fj);
                }
                a4a[i] = aa; a4b[i] = ab;
                p1 *= (1.0f - aa);
                p2 *= (1.0f - ab);
            }
            float sa = p1, sb = p2;
            #pragma unroll
            for (int o = 1; o < 16; o <<= 1) {
                float ua = __shfl_up(sa, (unsigned)o, 64);
                float ub = __shfl_up(sb, (unsigned)o, 64);
                if ((lane & 15) >= o) { sa *= ua; sb *= ub; }
            }
            float exa = __shfl_up(sa, 1u, 64);
            float exb = __shfl_up(sb, 1u, 64);
            const bool l0 = ((lane & 15) == 0);
            float Ta = base[(size_t)e*16 + e_px] * (l0 ? 1.0f : exa);
            unsigned short* swpa = &s_w16[0][e_kg >> 1][e_px][(e_kg & 1) << 2];
            #pragma unroll
            for (int i = 0; i < 4; ++i) {
                float wv_ = a4a[i] * Ta; Ta -= wv_;
                swpa[i] = f2bf(wv_);
            }
            if (pair) {
                float Tb = base[(size_t)(e+1)*16 + e_px] * (l0 ? 1.0f : exb);
                unsigned short* swpb = &s_w16[1][e_kg >> 1][e_px][(e_kg & 1) << 2];
                #pragma unroll
                for (int i = 0; i < 4; ++i) {
                    float wv_ = a4b[i] * Tb; Tb -= wv_;
                    swpb[i] = f2bf(wv_);
                }
            }
        }
        __syncthreads();   // s_w16 ready
        // ---- phase A: 4 (or 8) MFMA per wave; all B-gathers issued together ----
        {
            bf16x8 af0 = *(const bf16x8*)&s_w16[0][kb][m16][0];
            bf16x8 af1 = *(const bf16x8*)&s_w16[0][4 + kb][m16][0];
            bf16x8 bA0, bB0, bA1, bB1;
            #pragma unroll
            for (int j = 0; j < 8; ++j) {
                int g0i = slist[e & 3][(kb << 3) + j];
                int g1i = slist[e & 3][32 + (kb << 3) + j];
                const unsigned short* cp0 = colors16 + ((size_t)g0i << 7);
                const unsigned short* cp1 = colors16 + ((size_t)g1i << 7);
                bA0[j] = (short)cp0[chA]; bB0[j] = (short)cp0[chB];
                bA1[j] = (short)cp1[chA]; bB1[j] = (short)cp1[chB];
            }
            if (pair) {
                bf16x8 cf0 = *(const bf16x8*)&s_w16[1][kb][m16][0];
                bf16x8 cf1 = *(const bf16x8*)&s_w16[1][4 + kb][m16][0];
                bf16x8 dA0, dB0, dA1, dB1;
                #pragma unroll
                for (int j = 0; j < 8; ++j) {
                    int g0i = slist[(e+1) & 3][(kb << 3) + j];
                    int g1i = slist[(e+1) & 3][32 + (kb << 3) + j];
                    const unsigned short* cp0 = colors16 + ((size_t)g0i << 7);
                    const unsigned short* cp1 = colors16 + ((size_t)g1i << 7);
                    dA0[j] = (short)cp0[chA]; dB0[j] = (short)cp0[chB];
                    dA1[j] = (short)cp1[chA]; dB1[j] = (short)cp1[chB];
                }
                accA = __builtin_amdgcn_mfma_f32_16x16x32_bf16(af0, bA0, accA, 0, 0, 0);
                accB = __builtin_amdgcn_mfma_f32_16x16x32_bf16(af0, bB0, accB, 0, 0, 0);
                accA = __builtin_amdgcn_mfma_f32_16x16x32_bf16(af1, bA1, accA, 0, 0, 0);
                accB = __builtin_amdgcn_mfma_f32_16x16x32_bf16(af1, bB1, accB, 0, 0, 0);
                accA = __builtin_amdgcn_mfma_f32_16x16x32_bf16(cf0, dA0, accA, 0, 0, 0);
                accB = __builtin_amdgcn_mfma_f32_16x16x32_bf16(cf0, dB0, accB, 0, 0, 0);
                accA = __builtin_amdgcn_mfma_f32_16x16x32_bf16(cf1, dA1, accA, 0, 0, 0);
                accB = __builtin_amdgcn_mfma_f32_16x16x32_bf16(cf1, dB1, accB, 0, 0, 0);
            } else {
                accA = __builtin_amdgcn_mfma_f32_16x16x32_bf16(af0, bA0, accA, 0, 0, 0);
                accB = __builtin_amdgcn_mfma_f32_16x16x32_bf16(af0, bB0, accB, 0, 0, 0);
                accA = __builtin_amdgcn_mfma_f32_16x16x32_bf16(af1, bA1, accA, 0, 0, 0);
                accB = __builtin_amdgcn_mfma_f32_16x16x32_bf16(af1, bB1, accB, 0, 0, 0);
            }
        }
        e += pair ? 2 : 1;
    }
    // ---- final flush ----
    {
        const int cs4A = (wv_id << 3) + (m16 >> 2);
        const int compA = m16 & 3;
        #pragma unroll
        for (int r = 0; r < 4; ++r) {
            fred[((kb << 5) + cs4A)*17 + (r << 2) + compA]     = accA[r];
            fred[((kb << 5) + cs4A + 4)*17 + (r << 2) + compA] = accB[r];
        }
    }
    __syncthreads();
    {
        const float* f0 = &fred[(f_r0*32 + cs4r)*17 + (f_j<<2)];
        const float* f1 = &fred[((f_r0+2)*32 + cs4r)*17 + (f_j<<2)];
        const int pix0 = (cur_i0 + f_r0) * BEVW + cur_j0 + f_j;
        const int pix1 = pix0 + 2 * BEVW;
        float* op = out + (size_t)(cs4r << 2) * NPXB;
        atomicAdd(op + 0*NPXB + pix0, f0[0]); atomicAdd(op + 1*NPXB + pix0, f0[1]);
        atomicAdd(op + 2*NPXB + pix0, f0[2]); atomicAdd(op + 3*NPXB + pix0, f0[3]);
        atomicAdd(op + 0*NPXB + pix1, f1[0]); atomicAdd(op + 1*NPXB + pix1, f1[1]);
        atomicAdd(op + 2*NPXB + pix1, f1[2]); atomicAdd(op + 3*NPXB + pix1, f1[3]);
    }
}

extern "C" void kernel_launch(void* const* d_in, const int* in_sizes, int n_in,
                              void* d_out, int out_size, void* d_ws, size_t ws_size,
                              hipStream_t stream) {
    const float* rot  = (const float*)d_in[0];
    const float* tr   = (const float*)d_in[1];
    const float* intr = (const float*)d_in[2];
    const float* prot = (const float*)d_in[3];
    const float* ptr_ = (const float*)d_in[4];
    const float* img  = (const float*)d_in[5];
    const float* c1w  = (const float*)d_in[6];  const float* c1b = (const float*)d_in[7];
    const float* b1g  = (const float*)d_in[8];  const float* b1b = (const float*)d_in[9];
    const float* b1m  = (const float*)d_in[10]; const float* b1v = (const float*)d_in[11];
    const float* c2w  = (const float*)d_in[12]; const float* c2b = (const float*)d_in[13];
    const float* b2g  = (const float*)d_in[14]; const float* b2b = (const float*)d_in[15];
    const float* b2m  = (const float*)d_in[16]; const float* b2v = (const float*)d_in[17];
    const float* c3w  = (const float*)d_in[18]; const float* c3b = (const float*)d_in[19];
    float* out = (float*)d_out;
    float* ws  = (float*)d_ws;
    unsigned short* PAD16 = (unsigned short*)(ws + WS_A);          // also conv2out16
    unsigned short* C1O16 = (unsigned short*)(ws + WS_A + C1OFF);
    unsigned short* COL16 = (unsigned short*)(ws + WS_RB);
    float* X3B = ws + WS_X3;
    unsigned short* WC1 = (unsigned short*)X3B;                    // dead until conv1x1
    unsigned short* WC2 = WC1 + WELEM;
    float* GS  = ws + WS_GS;
    int*   WL  = (int*)(ws + WS_WL);
    float* BASE = ws + WS_BASE;
    unsigned long long* MASKS = (unsigned long long*)BASE;
    int* AUXI = (int*)(ws + WS_X3 + 330000);
    int* CNT = AUXI;           // 625
    int* OFF = AUXI + 640;     // 626
    int* CHOFF = AUXI + 1280;  // 626
    int* NWORK = AUXI + 1920;  // 1
    unsigned short* LIST = (unsigned short*)(ws + WS_A);           // after convs dead
    float* ngp = out + (size_t)NPXB*OUTC;

    prep_weights_kernel<<<(2*WELEM + 255)/256, 256, 0, stream>>>(c1w, c2w, WC1, WC2);
    pad_tr_kernel<<<NCAM*PH, 256, 0, stream>>>(img, PAD16, C1O16, out, MASKS);
    conv3x3_mfma_kernel<<<dim3(NCAM,64,2), 256, 0, stream>>>(PAD16, C1O16, WC1,
                                                             c1b, b1g, b1b, b1m, b1v);
    conv3x3_mfma_kernel<<<dim3(NCAM,64,2), 256, 0, stream>>>(C1O16, PAD16, WC2,
                                                             c2b, b2g, b2b, b2m, b2v);
    conv1x1_kernel<<<dim3(NCAM,11,22), 256, 0, stream>>>(PAD16, X3B, COL16, c3w, c3b);
    moments_kernel<<<GTOT/256, 256, 0, stream>>>(X3B, rot, tr, intr, prot, ptr_, GS, ngp);
    scatter_masks_kernel<<<GTOT*4/256, 256, 0, stream>>>(GS, MASKS);
    cnt_kernel<<<NTILE*NTILE, 256, 0, stream>>>(MASKS, CNT);
    scan_kernel<<<1, 640, 0, stream>>>(CNT, OFF, CHOFF, NWORK);
    fill_kernel<<<NTILE*NTILE, 256, 0, stream>>>(MASKS, CNT, OFF, CHOFF, LIST, WL);
    chunk_sums_kernel<<<8192, 256, 0, stream>>>(GS, LIST, CNT, OFF, WL, NWORK, BASE);
    chunk_prefix_kernel<<<NTILE*NTILE, 256, 0, stream>>>(CHOFF, BASE);
    composite_kernel<<<CBLK, 256, 0, stream>>>(GS, COL16, LIST, CNT, OFF, WL, NWORK, BASE, out);
}